// Round 8
// baseline (309.698 us; speedup 1.0000x reference)
//
#include <hip/hip_runtime.h>
#include <hip/hip_bf16.h>

// out[i] = x_i @ Q @ x_i, x [1024,2048] fp32 binary, Q [2048,2048] fp32.
// Identity: x^T Q x == x^T Q^T x -> MFMA B-operand (N x K) = row-major Q.
// Round 8: R6 structure (best so far: prep->bf16, 16x16x32 engine, XOR
// swizzle, global_load_lds, KSPLIT=16, contention-free partials, LDS-mask
// epilogue) + the reduce kernel FOLDED into qubo via the split-K
// last-block-done pattern (device-scope arrival counter per m-row-block;
// 256th block for each y reduces 128 rows x 256 partials from hot L2 and
// writes out). Saves one dispatch + launch gap; reduction overlaps the tail.

#define B_ROWS 1024
#define N_BITS 2048

#define BM 128
#define BN 128
#define BK 64
#define KSPLIT 16
#define KPER (N_BITS / KSPLIT)   // 128
#define KITERS (KPER / BK)       // 2
#define NKB (N_BITS / BN)        // 16 n-blocks
#define NPART (NKB * KSPLIT)     // 256 partials per row
#define MBLK (B_ROWS / BM)       // 8 m-row-blocks

typedef __bf16 bf16_t;
typedef __bf16 bf16x8 __attribute__((ext_vector_type(8)));
typedef float f32x4 __attribute__((ext_vector_type(4)));

__device__ __forceinline__ void load16_to_lds(const void* g, void* l) {
  __builtin_amdgcn_global_load_lds(
      (__attribute__((address_space(1))) void*)(g),
      (__attribute__((address_space(3))) void*)(l),
      16, 0, 0);
}

// prep: fp32 -> bf16 for x (2M) and Q (4M) into ws; zero arrival counters.
__global__ __launch_bounds__(256) void prep_kernel(
    const float* __restrict__ x, const float* __restrict__ Q,
    bf16_t* __restrict__ xb, bf16_t* __restrict__ qb, int* __restrict__ cnt) {
  const int tid = blockIdx.x * 256 + threadIdx.x;
  if (tid < MBLK) cnt[tid] = 0;
  const int XTH = (B_ROWS * N_BITS) / 8;  // 262144 threads cover x
  const float* src;
  bf16_t* dst;
  if (tid < XTH) {
    size_t o = (size_t)tid * 8;
    src = x + o;
    dst = xb + o;
  } else {
    size_t o = (size_t)(tid - XTH) * 8;
    src = Q + o;
    dst = qb + o;
  }
  float4 v0 = ((const float4*)src)[0];
  float4 v1 = ((const float4*)src)[1];
  union { int4 i4; __hip_bfloat16 h[8]; } u;
  u.h[0] = __float2bfloat16(v0.x);
  u.h[1] = __float2bfloat16(v0.y);
  u.h[2] = __float2bfloat16(v0.z);
  u.h[3] = __float2bfloat16(v0.w);
  u.h[4] = __float2bfloat16(v1.x);
  u.h[5] = __float2bfloat16(v1.y);
  u.h[6] = __float2bfloat16(v1.z);
  u.h[7] = __float2bfloat16(v1.w);
  ((int4*)dst)[0] = u.i4;
}

// GEMM S = Xb @ Qb^T (16x16x32 frags) + LDS-masked row-dot + split-K
// last-block reduction. 4 waves split M (32 rows x 128 cols each, acc 2x8).
__global__ __launch_bounds__(256) void qubo_kernel(
    const bf16_t* __restrict__ Xb, const bf16_t* __restrict__ Qb,
    float* __restrict__ partial, int* __restrict__ cnt,
    float* __restrict__ out) {
  __shared__ bf16_t lds[(BM + BN) * BK];   // 32 KB; A at 0, B at BM*BK
  __shared__ int arrivals;
  bf16_t* ldsA = lds;
  bf16_t* ldsB = lds + BM * BK;

  const int tid  = threadIdx.x;
  const int lane = tid & 63;
  const int wave = tid >> 6;     // 0..3 -> owns rows [wave*32, wave*32+32)
  const int lrow = lane & 15;
  const int quad = lane >> 4;

  const int m0    = blockIdx.y * BM;
  const int n0    = blockIdx.x * BN;
  const int kbase = blockIdx.z * KPER;
  const int nkid  = blockIdx.x * KSPLIT + blockIdx.z;  // 0..255

  // Staging (R6-verified): 32 rows x 8 chunks (16B) per pass; LDS dest linear
  // in tid (== wave_base + lane*16B as global_load_lds requires); GLOBAL chunk
  // XOR-swizzled: LDS slot s of row r holds global chunk s ^ (r&7).
  const int srow = tid >> 3;                // 0..31
  const int gch  = (tid & 7) ^ (srow & 7);  // swizzled global chunk

  f32x4 acc[2][8];
#pragma unroll
  for (int i = 0; i < 2; ++i)
#pragma unroll
    for (int j = 0; j < 8; ++j) acc[i][j] = (f32x4){0.f, 0.f, 0.f, 0.f};

  for (int kt = 0; kt < KITERS; ++kt) {
    const int k0 = kbase + kt * BK;
#pragma unroll
    for (int p = 0; p < 4; ++p) {
      const int r = p * 32 + srow;
      load16_to_lds(Xb + (size_t)(m0 + r) * N_BITS + k0 + gch * 8,
                    ldsA + r * BK + (tid & 7) * 8);
      load16_to_lds(Qb + (size_t)(n0 + r) * N_BITS + k0 + gch * 8,
                    ldsB + r * BK + (tid & 7) * 8);
    }
    __syncthreads();

    const int sw = lrow & 7;
#pragma unroll
    for (int ks = 0; ks < 2; ++ks) {
      const int ch = ((ks * 4 + quad) ^ sw) * 8;  // un-swizzled chunk offset
      bf16x8 a[2], b[8];
#pragma unroll
      for (int mi = 0; mi < 2; ++mi)
        a[mi] = *(const bf16x8*)&ldsA[(wave * 32 + mi * 16 + lrow) * BK + ch];
#pragma unroll
      for (int ni = 0; ni < 8; ++ni)
        b[ni] = *(const bf16x8*)&ldsB[(ni * 16 + lrow) * BK + ch];
#pragma unroll
      for (int mi = 0; mi < 2; ++mi)
#pragma unroll
        for (int ni = 0; ni < 8; ++ni)
          acc[mi][ni] = __builtin_amdgcn_mfma_f32_16x16x32_bf16(
              a[mi], b[ni], acc[mi][ni], 0, 0, 0);
    }
    __syncthreads();
  }

  // Stage x-mask tile X[m0:+128, n0:+128] (bf16, 32 KB) into the SAME lds:
  // 128 rows x 16 chunks = 8 per thread; dest linear per wave (R5/R6-verified).
  bf16_t* maskL = lds;
#pragma unroll
  for (int p = 0; p < 8; ++p) {
    const int r = p * 16 + (tid >> 4);
    load16_to_lds(Xb + (size_t)(m0 + r) * N_BITS + n0 + (tid & 15) * 8,
                  maskL + r * BN + (tid & 15) * 8);
  }
  __syncthreads();

  // Epilogue. 16x16 C/D: col = lane&15, row = quad*4 + reg. Mask from LDS,
  // 16-lane shuffle reduce, one plain store per (row, nkid). No atomics.
#pragma unroll
  for (int mi = 0; mi < 2; ++mi) {
#pragma unroll
    for (int r = 0; r < 4; ++r) {
      const int rloc = wave * 32 + mi * 16 + quad * 4 + r;
      float s = 0.f;
#pragma unroll
      for (int ni = 0; ni < 8; ++ni) {
        const int cloc = ni * 16 + lrow;
        s += acc[mi][ni][r] * (float)maskL[rloc * BN + cloc];
      }
#pragma unroll
      for (int off = 1; off < 16; off <<= 1)
        s += __shfl_xor(s, off, 64);
      if (lrow == 0)
        partial[(size_t)(m0 + rloc) * NPART + nkid] = s;
    }
  }

  // --- split-K completion: last arriving block for this y reduces. ---
  // CUDA threadFenceReduction pattern: every thread releases its stores,
  // then tid0 arrives with a device-scope acq_rel atomic.
  __threadfence();            // release partial stores to device scope
  __syncthreads();
  if (tid == 0)
    arrivals = __hip_atomic_fetch_add(&cnt[blockIdx.y], 1,
                                      __ATOMIC_ACQ_REL,
                                      __HIP_MEMORY_SCOPE_AGENT);
  __syncthreads();
  if (arrivals == NPART - 1) {       // we are the last of 256 blocks for y
    __threadfence();                 // acquire: see all partials
    // Reduce 128 rows x 256 partials. Wave w handles rows w, w+4, ...;
    // each lane reads 4 coalesced strips of 64, shuffle-reduce, lane0 stores.
    for (int r = wave; r < BM; r += 4) {
      const float* p = partial + (size_t)(m0 + r) * NPART;
      float v = p[lane] + p[64 + lane] + p[128 + lane] + p[192 + lane];
#pragma unroll
      for (int off = 1; off < 64; off <<= 1)
        v += __shfl_xor(v, off, 64);
      if (lane == 0) out[m0 + r] = v;
    }
  }
}

extern "C" void kernel_launch(void* const* d_in, const int* in_sizes, int n_in,
                              void* d_out, int out_size, void* d_ws, size_t ws_size,
                              hipStream_t stream) {
  const float* x = (const float*)d_in[0];
  const float* Q = (const float*)d_in[1];
  float* out = (float*)d_out;

  bf16_t* xb = (bf16_t*)d_ws;                                        // 4 MB
  bf16_t* qb = (bf16_t*)((char*)d_ws + (size_t)B_ROWS * N_BITS * 2); // 8 MB
  float* partial = (float*)((char*)d_ws + (size_t)12 * 1024 * 1024); // 1 MB
  int* cnt = (int*)((char*)d_ws + (size_t)13 * 1024 * 1024);         // 32 B

  prep_kernel<<<3072, 256, 0, stream>>>(x, Q, xb, qb, cnt);

  dim3 grid(NKB, B_ROWS / BM, KSPLIT);  // (16, 8, 16) = 2048 blocks
  qubo_kernel<<<grid, dim3(256), 0, stream>>>(xb, qb, partial, cnt, out);
}

// Round 10
// 97.324 us; speedup vs baseline: 3.1821x; 3.1821x over previous
//
#include <hip/hip_runtime.h>
#include <hip/hip_bf16.h>

// out[i] = x_i @ Q @ x_i, x [1024,2048] fp32 binary, Q [2048,2048] fp32.
// Identity: x^T Q x == x^T Q^T x -> MFMA B-operand (N x K) = row-major Q.
// Round 10 (= R9 + compile fix): R6 engine (prep->bf16, 16x16x32 frags, XOR
// swizzle, global_load_lds, contention-free partials + reduce kernel — NO
// fences, R8's device-scope fence-per-block was a 13x disaster). NEW:
// (a) x mask as PACKED BITS (binary input -> 16 B per row-slice; 2 KB/block
// staged in the SAME barrier as A/B, epilogue uses broadcast ds_read_b64 +
// cndmask-adds), (b) KSPLIT=32 -> KITERS=1: ONE barrier per block, 4096
// blocks (~16/CU) for max latency overlap; A/B staged traffic KSPLIT-invariant.

#define B_ROWS 1024
#define N_BITS 2048

#define BM 128
#define BN 128
#define BK 64
#define KSPLIT 32
#define KPER (N_BITS / KSPLIT)   // 64  -> KITERS = 1
#define NKB (N_BITS / BN)        // 16 n-blocks
#define NPART (NKB * KSPLIT)     // 512 partials per row

typedef __bf16 bf16_t;
typedef __bf16 bf16x8 __attribute__((ext_vector_type(8)));
typedef float f32x4 __attribute__((ext_vector_type(4)));

__device__ __forceinline__ void load16_to_lds(const void* g, void* l) {
  __builtin_amdgcn_global_load_lds(
      (__attribute__((address_space(1))) void*)(g),
      (__attribute__((address_space(3))) void*)(l),
      16, 0, 0);
}

// prep: fp32 -> bf16 for x (2M) and Q (4M) into ws; pack x bits (1 byte per
// 8 elems, xpack[tid] for the x-range threads -> fully coalesced).
__global__ __launch_bounds__(256) void prep_kernel(
    const float* __restrict__ x, const float* __restrict__ Q,
    bf16_t* __restrict__ xb, bf16_t* __restrict__ qb,
    unsigned char* __restrict__ xpack) {
  const int tid = blockIdx.x * 256 + threadIdx.x;
  const int XTH = (B_ROWS * N_BITS) / 8;  // 262144 threads cover x
  const float* src;
  bf16_t* dst;
  const bool isX = tid < XTH;
  if (isX) {
    size_t o = (size_t)tid * 8;
    src = x + o;
    dst = xb + o;
  } else {
    size_t o = (size_t)(tid - XTH) * 8;
    src = Q + o;
    dst = qb + o;
  }
  float4 v0 = ((const float4*)src)[0];
  float4 v1 = ((const float4*)src)[1];
  union { int4 i4; __hip_bfloat16 h[8]; } u;
  u.h[0] = __float2bfloat16(v0.x);
  u.h[1] = __float2bfloat16(v0.y);
  u.h[2] = __float2bfloat16(v0.z);
  u.h[3] = __float2bfloat16(v0.w);
  u.h[4] = __float2bfloat16(v1.x);
  u.h[5] = __float2bfloat16(v1.y);
  u.h[6] = __float2bfloat16(v1.z);
  u.h[7] = __float2bfloat16(v1.w);
  ((int4*)dst)[0] = u.i4;
  if (isX) {
    unsigned int b = 0;
    b |= (v0.x != 0.f) << 0;
    b |= (v0.y != 0.f) << 1;
    b |= (v0.z != 0.f) << 2;
    b |= (v0.w != 0.f) << 3;
    b |= (v1.x != 0.f) << 4;
    b |= (v1.y != 0.f) << 5;
    b |= (v1.z != 0.f) << 6;
    b |= (v1.w != 0.f) << 7;
    xpack[tid] = (unsigned char)b;
  }
}

// GEMM S = Xb @ Qb^T (16x16x32 frags) + bit-masked row-dot -> partials.
// 4 waves split M (32 rows x 128 cols each, acc 2x8). ONE barrier total.
__global__ __launch_bounds__(256) void qubo_kernel(
    const bf16_t* __restrict__ Xb, const bf16_t* __restrict__ Qb,
    const unsigned char* __restrict__ xpack, float* __restrict__ partial) {
  __shared__ bf16_t ldsA[BM * BK];             // 16 KB
  __shared__ bf16_t ldsB[BN * BK];             // 16 KB
  __shared__ unsigned long long mbits[BM * 2]; // 2 KB: 128 bits per row

  const int tid  = threadIdx.x;
  const int lane = tid & 63;
  const int wave = tid >> 6;     // 0..3 -> owns rows [wave*32, wave*32+32)
  const int lrow = lane & 15;
  const int quad = lane >> 4;

  const int m0 = blockIdx.y * BM;
  const int n0 = blockIdx.x * BN;
  const int k0 = blockIdx.z * KPER;
  const int nkid = blockIdx.x * KSPLIT + blockIdx.z;  // 0..511

  // Staging (R6-verified math): 32 rows x 8 chunks (16B) per pass; LDS dest
  // linear in tid (wave_base + lane*16B per global_load_lds); GLOBAL chunk
  // XOR-swizzled: LDS slot s of row r holds global chunk s ^ (r&7).
  const int srow = tid >> 3;                // 0..31
  const int gch  = (tid & 7) ^ (srow & 7);  // swizzled global chunk

#pragma unroll
  for (int p = 0; p < 4; ++p) {
    const int r = p * 32 + srow;
    load16_to_lds(Xb + (size_t)(m0 + r) * N_BITS + k0 + gch * 8,
                  ldsA + r * BK + (tid & 7) * 8);
    load16_to_lds(Qb + (size_t)(n0 + r) * N_BITS + k0 + gch * 8,
                  ldsB + r * BK + (tid & 7) * 8);
  }
  // mask bits: 128 rows x 16 B, staged by waves 0-1 in the same vmcnt window.
  // xpack row stride = 256 B; this block's slice starts at byte n0/8 (16B-aligned).
  if (wave < 2) {
    const int r = tid;  // 0..127
    load16_to_lds(xpack + (size_t)(m0 + r) * (N_BITS / 8) + (n0 >> 3),
                  (void*)(mbits + r * 2));
  }

  f32x4 acc[2][8];
#pragma unroll
  for (int i = 0; i < 2; ++i)
#pragma unroll
    for (int j = 0; j < 8; ++j) acc[i][j] = (f32x4){0.f, 0.f, 0.f, 0.f};

  __syncthreads();   // the ONLY barrier: drains all global_load_lds

  const int sw = lrow & 7;
#pragma unroll
  for (int ks = 0; ks < 2; ++ks) {
    const int ch = ((ks * 4 + quad) ^ sw) * 8;  // un-swizzled chunk offset
    bf16x8 a[2], b[8];
#pragma unroll
    for (int mi = 0; mi < 2; ++mi)
      a[mi] = *(const bf16x8*)&ldsA[(wave * 32 + mi * 16 + lrow) * BK + ch];
#pragma unroll
    for (int ni = 0; ni < 8; ++ni)
      b[ni] = *(const bf16x8*)&ldsB[(ni * 16 + lrow) * BK + ch];
#pragma unroll
    for (int mi = 0; mi < 2; ++mi)
#pragma unroll
      for (int ni = 0; ni < 8; ++ni)
        acc[mi][ni] = __builtin_amdgcn_mfma_f32_16x16x32_bf16(
            a[mi], b[ni], acc[mi][ni], 0, 0, 0);
  }

  // Epilogue. 16x16 C/D: col = lane&15, row = quad*4 + reg. Bit-mask from LDS
  // (broadcast reads), cndmask-adds, 16-lane shuffle reduce, one plain store
  // per (row, nkid). No atomics, no fences.
#pragma unroll
  for (int mi = 0; mi < 2; ++mi) {
#pragma unroll
    for (int r = 0; r < 4; ++r) {
      const int rloc = wave * 32 + mi * 16 + quad * 4 + r;
      const unsigned long long w0 = mbits[rloc * 2];      // cols 0..63
      const unsigned long long w1 = mbits[rloc * 2 + 1];  // cols 64..127
      float s = 0.f;
#pragma unroll
      for (int ni = 0; ni < 4; ++ni)
        s += ((w0 >> (ni * 16 + lrow)) & 1ull) ? acc[mi][ni][r] : 0.f;
#pragma unroll
      for (int ni = 4; ni < 8; ++ni)
        s += ((w1 >> ((ni - 4) * 16 + lrow)) & 1ull) ? acc[mi][ni][r] : 0.f;
#pragma unroll
      for (int off = 1; off < 16; off <<= 1)
        s += __shfl_xor(s, off, 64);
      if (lrow == 0)
        partial[(size_t)(m0 + rloc) * NPART + nkid] = s;
    }
  }
}

// reduce: out[row] = sum of 512 partials. One block per row, coalesced.
__global__ __launch_bounds__(256) void reduce_kernel(
    const float* __restrict__ partial, float* __restrict__ out) {
  const int row = blockIdx.x;
  const int tid = threadIdx.x;
  const float* p = partial + (size_t)row * NPART;
  float v = p[tid] + p[256 + tid];
#pragma unroll
  for (int off = 1; off < 64; off <<= 1)
    v += __shfl_xor(v, off, 64);
  __shared__ float wsum[4];
  if ((tid & 63) == 0) wsum[tid >> 6] = v;
  __syncthreads();
  if (tid == 0) out[row] = wsum[0] + wsum[1] + wsum[2] + wsum[3];
}

extern "C" void kernel_launch(void* const* d_in, const int* in_sizes, int n_in,
                              void* d_out, int out_size, void* d_ws, size_t ws_size,
                              hipStream_t stream) {
  const float* x = (const float*)d_in[0];
  const float* Q = (const float*)d_in[1];
  float* out = (float*)d_out;

  bf16_t* xb = (bf16_t*)d_ws;                                              // 4 MB @ 0
  bf16_t* qb = (bf16_t*)((char*)d_ws + (size_t)B_ROWS * N_BITS * 2);       // 8 MB @ 4M
  unsigned char* xpack = (unsigned char*)((char*)d_ws + ((size_t)12 << 20)); // 256 KB @ 12M
  float* partial = (float*)((char*)d_ws + ((size_t)13 << 20));             // 2 MB @ 13M

  prep_kernel<<<3072, 256, 0, stream>>>(x, Q, xb, qb, xpack);

  dim3 grid(NKB, B_ROWS / BM, KSPLIT);  // (16, 8, 32) = 4096 blocks
  qubo_kernel<<<grid, dim3(256), 0, stream>>>(xb, qb, xpack, partial);

  reduce_kernel<<<B_ROWS, 256, 0, stream>>>(partial, out);
}

// Round 11
// 90.475 us; speedup vs baseline: 3.4230x; 1.0757x over previous
//
#include <hip/hip_runtime.h>
#include <hip/hip_bf16.h>

// out[i] = x_i @ Q @ x_i, x [1024,2048] fp32 binary, Q [2048,2048] fp32.
// Identity: x^T Q x == x^T Q^T x -> MFMA B-operand (N x K) = row-major Q.
// Round 11 = R6 (best: KSPLIT=16, 2048 blocks, 16x16x32 engine, XOR swizzle,
// global_load_lds, contention-free partials + reduce) + R10's bit-packed x
// mask (exact for binary input) staged INSIDE iter-0's vmcnt window: kills
// R6's third staging phase (64 MB traffic + one global-latency barrier).
// 3 barriers/block total. No atomics, no fences (R8 lesson).

#define B_ROWS 1024
#define N_BITS 2048

#define BM 128
#define BN 128
#define BK 64
#define KSPLIT 16
#define KPER (N_BITS / KSPLIT)   // 128 -> KITERS = 2
#define KITERS (KPER / BK)
#define NKB (N_BITS / BN)        // 16 n-blocks
#define NPART (NKB * KSPLIT)     // 256 partials per row

typedef __bf16 bf16_t;
typedef __bf16 bf16x8 __attribute__((ext_vector_type(8)));
typedef float f32x4 __attribute__((ext_vector_type(4)));

__device__ __forceinline__ void load16_to_lds(const void* g, void* l) {
  __builtin_amdgcn_global_load_lds(
      (__attribute__((address_space(1))) void*)(g),
      (__attribute__((address_space(3))) void*)(l),
      16, 0, 0);
}

// prep: fp32 -> bf16 for x (2M) and Q (4M) into ws; pack x bits (1 byte per
// 8 elems, xpack[tid] for x-range threads -> fully coalesced).
__global__ __launch_bounds__(256) void prep_kernel(
    const float* __restrict__ x, const float* __restrict__ Q,
    bf16_t* __restrict__ xb, bf16_t* __restrict__ qb,
    unsigned char* __restrict__ xpack) {
  const int tid = blockIdx.x * 256 + threadIdx.x;
  const int XTH = (B_ROWS * N_BITS) / 8;  // 262144 threads cover x
  const float* src;
  bf16_t* dst;
  const bool isX = tid < XTH;
  if (isX) {
    size_t o = (size_t)tid * 8;
    src = x + o;
    dst = xb + o;
  } else {
    size_t o = (size_t)(tid - XTH) * 8;
    src = Q + o;
    dst = qb + o;
  }
  float4 v0 = ((const float4*)src)[0];
  float4 v1 = ((const float4*)src)[1];
  union { int4 i4; __hip_bfloat16 h[8]; } u;
  u.h[0] = __float2bfloat16(v0.x);
  u.h[1] = __float2bfloat16(v0.y);
  u.h[2] = __float2bfloat16(v0.z);
  u.h[3] = __float2bfloat16(v0.w);
  u.h[4] = __float2bfloat16(v1.x);
  u.h[5] = __float2bfloat16(v1.y);
  u.h[6] = __float2bfloat16(v1.z);
  u.h[7] = __float2bfloat16(v1.w);
  ((int4*)dst)[0] = u.i4;
  if (isX) {
    unsigned int b = 0;
    b |= (v0.x != 0.f) << 0;
    b |= (v0.y != 0.f) << 1;
    b |= (v0.z != 0.f) << 2;
    b |= (v0.w != 0.f) << 3;
    b |= (v1.x != 0.f) << 4;
    b |= (v1.y != 0.f) << 5;
    b |= (v1.z != 0.f) << 6;
    b |= (v1.w != 0.f) << 7;
    xpack[tid] = (unsigned char)b;
  }
}

// GEMM S = Xb @ Qb^T (16x16x32 frags) + bit-masked row-dot -> partials.
// 4 waves split M (32 rows x 128 cols each, acc 2x8). 3 barriers total.
__global__ __launch_bounds__(256) void qubo_kernel(
    const bf16_t* __restrict__ Xb, const bf16_t* __restrict__ Qb,
    const unsigned char* __restrict__ xpack, float* __restrict__ partial) {
  __shared__ bf16_t ldsA[BM * BK];             // 16 KB
  __shared__ bf16_t ldsB[BN * BK];             // 16 KB
  __shared__ unsigned long long mbits[BM * 2]; // 2 KB: 128 bits per row

  const int tid  = threadIdx.x;
  const int lane = tid & 63;
  const int wave = tid >> 6;     // 0..3 -> owns rows [wave*32, wave*32+32)
  const int lrow = lane & 15;
  const int quad = lane >> 4;

  const int m0    = blockIdx.y * BM;
  const int n0    = blockIdx.x * BN;
  const int kbase = blockIdx.z * KPER;
  const int nkid  = blockIdx.x * KSPLIT + blockIdx.z;  // 0..255

  // Staging (R6-verified): 32 rows x 8 chunks (16B) per pass; LDS dest linear
  // in tid (wave_base + lane*16B per global_load_lds); GLOBAL chunk
  // XOR-swizzled: LDS slot s of row r holds global chunk s ^ (r&7).
  const int srow = tid >> 3;                // 0..31
  const int gch  = (tid & 7) ^ (srow & 7);  // swizzled global chunk

  f32x4 acc[2][8];
#pragma unroll
  for (int i = 0; i < 2; ++i)
#pragma unroll
    for (int j = 0; j < 8; ++j) acc[i][j] = (f32x4){0.f, 0.f, 0.f, 0.f};

  for (int kt = 0; kt < KITERS; ++kt) {
    const int k0 = kbase + kt * BK;
#pragma unroll
    for (int p = 0; p < 4; ++p) {
      const int r = p * 32 + srow;
      load16_to_lds(Xb + (size_t)(m0 + r) * N_BITS + k0 + gch * 8,
                    ldsA + r * BK + (tid & 7) * 8);
      load16_to_lds(Qb + (size_t)(n0 + r) * N_BITS + k0 + gch * 8,
                    ldsB + r * BK + (tid & 7) * 8);
    }
    // mask bits ride iter-0's vmcnt window: 128 rows x 16 B by waves 0-1
    // (R10-verified: wave-uniform base + lane*16 dest).
    if (kt == 0 && wave < 2) {
      load16_to_lds(xpack + (size_t)(m0 + tid) * (N_BITS / 8) + (n0 >> 3),
                    (void*)(mbits + tid * 2));
    }
    __syncthreads();

    const int sw = lrow & 7;
#pragma unroll
    for (int ks = 0; ks < 2; ++ks) {
      const int ch = ((ks * 4 + quad) ^ sw) * 8;  // un-swizzled chunk offset
      bf16x8 a[2], b[8];
#pragma unroll
      for (int mi = 0; mi < 2; ++mi)
        a[mi] = *(const bf16x8*)&ldsA[(wave * 32 + mi * 16 + lrow) * BK + ch];
#pragma unroll
      for (int ni = 0; ni < 8; ++ni)
        b[ni] = *(const bf16x8*)&ldsB[(ni * 16 + lrow) * BK + ch];
#pragma unroll
      for (int mi = 0; mi < 2; ++mi)
#pragma unroll
        for (int ni = 0; ni < 8; ++ni)
          acc[mi][ni] = __builtin_amdgcn_mfma_f32_16x16x32_bf16(
              a[mi], b[ni], acc[mi][ni], 0, 0, 0);
    }
    if (kt + 1 < KITERS) __syncthreads();  // protect LDS before next stage
  }

  // Epilogue. 16x16 C/D: col = lane&15, row = quad*4 + reg. Bit-mask from LDS
  // (broadcast reads), cndmask-adds, 16-lane shuffle reduce, one plain store
  // per (row, nkid). No atomics, no fences.
#pragma unroll
  for (int mi = 0; mi < 2; ++mi) {
#pragma unroll
    for (int r = 0; r < 4; ++r) {
      const int rloc = wave * 32 + mi * 16 + quad * 4 + r;
      const unsigned long long w0 = mbits[rloc * 2];      // cols 0..63
      const unsigned long long w1 = mbits[rloc * 2 + 1];  // cols 64..127
      float s = 0.f;
#pragma unroll
      for (int ni = 0; ni < 4; ++ni)
        s += ((w0 >> (ni * 16 + lrow)) & 1ull) ? acc[mi][ni][r] : 0.f;
#pragma unroll
      for (int ni = 4; ni < 8; ++ni)
        s += ((w1 >> ((ni - 4) * 16 + lrow)) & 1ull) ? acc[mi][ni][r] : 0.f;
#pragma unroll
      for (int off = 1; off < 16; off <<= 1)
        s += __shfl_xor(s, off, 64);
      if (lrow == 0)
        partial[(size_t)(m0 + rloc) * NPART + nkid] = s;
    }
  }
}

// reduce: out[row] = sum of 256 partials. One block per row, coalesced.
__global__ __launch_bounds__(256) void reduce_kernel(
    const float* __restrict__ partial, float* __restrict__ out) {
  const int row = blockIdx.x;
  const int tid = threadIdx.x;
  float v = partial[(size_t)row * NPART + tid];
#pragma unroll
  for (int off = 1; off < 64; off <<= 1)
    v += __shfl_xor(v, off, 64);
  __shared__ float wsum[4];
  if ((tid & 63) == 0) wsum[tid >> 6] = v;
  __syncthreads();
  if (tid == 0) out[row] = wsum[0] + wsum[1] + wsum[2] + wsum[3];
}

extern "C" void kernel_launch(void* const* d_in, const int* in_sizes, int n_in,
                              void* d_out, int out_size, void* d_ws, size_t ws_size,
                              hipStream_t stream) {
  const float* x = (const float*)d_in[0];
  const float* Q = (const float*)d_in[1];
  float* out = (float*)d_out;

  bf16_t* xb = (bf16_t*)d_ws;                                              // 4 MB @ 0
  bf16_t* qb = (bf16_t*)((char*)d_ws + (size_t)B_ROWS * N_BITS * 2);       // 8 MB @ 4M
  unsigned char* xpack = (unsigned char*)((char*)d_ws + ((size_t)12 << 20)); // 256 KB @ 12M
  float* partial = (float*)((char*)d_ws + ((size_t)13 << 20));             // 1 MB @ 13M

  prep_kernel<<<3072, 256, 0, stream>>>(x, Q, xb, qb, xpack);

  dim3 grid(NKB, B_ROWS / BM, KSPLIT);  // (16, 8, 16) = 2048 blocks
  qubo_kernel<<<grid, dim3(256), 0, stream>>>(xb, qb, xpack, partial);

  reduce_kernel<<<B_ROWS, 256, 0, stream>>>(partial, out);
}

// Round 12
// 89.351 us; speedup vs baseline: 3.4661x; 1.0126x over previous
//
#include <hip/hip_runtime.h>
#include <hip/hip_bf16.h>

// out[i] = x_i @ Q @ x_i, x [1024,2048] fp32 binary, Q [2048,2048] fp32.
// Identity: x^T Q x == x^T Q^T x -> MFMA B-operand (N x K) = row-major Q.
// Round 12: A-operand (binary x) is NEVER materialized as bf16 — lanes load
// 16 B of bit-packed x and expand 8-bit chunks to bf16 {0,1} in registers
// (cndmask, runs on VALU pipe concurrent with MFMA). Kills A staging (16 KB
// LDS + 32 MB L2 traffic + 8 ds_read/wave) and xb from prep. With A out of
// LDS, BK=128: ONE staging window + ONE barrier per block, same 2048 blocks
// (KSPLIT=16, R10 showed block-count must not grow). Partials + reduce, no
// atomics, no fences (R8 lesson). Bit-mask epilogue (R11-verified).

#define B_ROWS 1024
#define N_BITS 2048

#define BM 128
#define BN 128
#define BK 128                   // = KPER, single tile
#define KSPLIT 16
#define KPER (N_BITS / KSPLIT)   // 128
#define NKB (N_BITS / BN)        // 16 n-blocks
#define NPART (NKB * KSPLIT)     // 256 partials per row

typedef __bf16 bf16_t;
typedef __bf16 bf16x8 __attribute__((ext_vector_type(8)));
typedef float f32x4 __attribute__((ext_vector_type(4)));

__device__ __forceinline__ void load16_to_lds(const void* g, void* l) {
  __builtin_amdgcn_global_load_lds(
      (__attribute__((address_space(1))) void*)(g),
      (__attribute__((address_space(3))) void*)(l),
      16, 0, 0);
}

// 8 bits -> 8 bf16 {0.0, 1.0}; explicit per-bit selects (no dynamic local
// array indexing -> no scratch).
__device__ __forceinline__ bf16x8 expand8(unsigned int byte) {
  union { bf16x8 v; unsigned int w[4]; } u;
#pragma unroll
  for (int p = 0; p < 4; ++p) {
    const unsigned int lo = (byte & (1u << (2 * p)))     ? 0x00003F80u : 0u;
    const unsigned int hi = (byte & (1u << (2 * p + 1))) ? 0x3F800000u : 0u;
    u.w[p] = lo | hi;
  }
  return u.v;
}

// prep: fp32 -> bf16 for Q (4M elems) into ws; pack x bits (1 byte / 8 elems).
__global__ __launch_bounds__(256) void prep_kernel(
    const float* __restrict__ x, const float* __restrict__ Q,
    bf16_t* __restrict__ qb, unsigned char* __restrict__ xpack) {
  const int tid = blockIdx.x * 256 + threadIdx.x;
  const int PTH = (B_ROWS * N_BITS) / 8;  // 262144 pack threads
  if (tid < PTH) {
    const float4* s = (const float4*)(x + (size_t)tid * 8);
    float4 v0 = s[0];
    float4 v1 = s[1];
    unsigned int b = 0;
    b |= (v0.x != 0.f) << 0;
    b |= (v0.y != 0.f) << 1;
    b |= (v0.z != 0.f) << 2;
    b |= (v0.w != 0.f) << 3;
    b |= (v1.x != 0.f) << 4;
    b |= (v1.y != 0.f) << 5;
    b |= (v1.z != 0.f) << 6;
    b |= (v1.w != 0.f) << 7;
    xpack[tid] = (unsigned char)b;
  } else {
    const size_t o = (size_t)(tid - PTH) * 8;
    const float4* s = (const float4*)(Q + o);
    float4 v0 = s[0];
    float4 v1 = s[1];
    union { int4 i4; __hip_bfloat16 h[8]; } u;
    u.h[0] = __float2bfloat16(v0.x);
    u.h[1] = __float2bfloat16(v0.y);
    u.h[2] = __float2bfloat16(v0.z);
    u.h[3] = __float2bfloat16(v0.w);
    u.h[4] = __float2bfloat16(v1.x);
    u.h[5] = __float2bfloat16(v1.y);
    u.h[6] = __float2bfloat16(v1.z);
    u.h[7] = __float2bfloat16(v1.w);
    ((int4*)(qb + o))[0] = u.i4;
  }
}

// GEMM S = bits(X) @ Qb^T (16x16x32 frags) + bit-masked row-dot -> partials.
// 4 waves split M (32 rows x 128 cols each, acc 2x8). ONE barrier per block.
__global__ __launch_bounds__(256) void qubo_kernel(
    const bf16_t* __restrict__ Qb, const unsigned char* __restrict__ xpack,
    float* __restrict__ partial) {
  __shared__ bf16_t ldsB[BN * BK];             // 32 KB
  __shared__ unsigned long long mbits[BM * 2]; // 2 KB: 128 n-bits per row

  const int tid  = threadIdx.x;
  const int lane = tid & 63;
  const int wave = tid >> 6;     // 0..3 -> owns rows [wave*32, wave*32+32)
  const int lrow = lane & 15;
  const int quad = lane >> 4;

  const int m0    = blockIdx.y * BM;
  const int n0    = blockIdx.x * BN;
  const int kbase = blockIdx.z * KPER;
  const int nkid  = blockIdx.x * KSPLIT + blockIdx.z;  // 0..255

  // B staging: 128 rows x 16 chunks (16B) = 8 per thread. LDS dest linear in
  // tid (byte off = p*4096 + tid*16, wave-uniform base + lane*16 as
  // global_load_lds requires). GLOBAL chunk XOR-swizzled: LDS slot s of row r
  // holds global chunk s ^ (r&15) -> frag reads 2-way banked (free).
  const int srow = tid >> 4;        // 0..15
  const int slot = tid & 15;
  const int gch  = slot ^ srow;     // r&15 == srow for every pass
#pragma unroll
  for (int p = 0; p < 8; ++p) {
    const int r = p * 16 + srow;
    load16_to_lds(Qb + (size_t)(n0 + r) * N_BITS + kbase + gch * 8,
                  ldsB + r * BK + slot * 8);
  }
  // mask bits (n0-slice): 128 rows x 16 B by waves 0-1, same vmcnt window.
  if (wave < 2) {
    load16_to_lds(xpack + (size_t)(m0 + tid) * (N_BITS / 8) + (n0 >> 3),
                  (void*)(mbits + tid * 2));
  }

  // A bits (k-slice): 16 B per owned row, straight to registers — no barrier
  // dependency. 4 lanes/row redundancy is L1-broadcast.
  unsigned long long abits[2][2];
#pragma unroll
  for (int mi = 0; mi < 2; ++mi) {
    const int row = m0 + wave * 32 + mi * 16 + lrow;
    const unsigned long long* ap =
        (const unsigned long long*)(xpack + (size_t)row * (N_BITS / 8) +
                                    (kbase >> 3));
    abits[mi][0] = ap[0];
    abits[mi][1] = ap[1];
  }

  f32x4 acc[2][8];
#pragma unroll
  for (int i = 0; i < 2; ++i)
#pragma unroll
    for (int j = 0; j < 8; ++j) acc[i][j] = (f32x4){0.f, 0.f, 0.f, 0.f};

  __syncthreads();   // the ONLY barrier: drains B + mask staging

#pragma unroll
  for (int ks = 0; ks < 4; ++ks) {
    const int c  = ks * 4 + quad;        // chunk index 0..15 (k = c*8..c*8+7)
    const int ch = (c ^ lrow) * 8;       // un-swizzle (frag row & 15 == lrow)
    bf16x8 b[8], a[2];
#pragma unroll
    for (int ni = 0; ni < 8; ++ni)
      b[ni] = *(const bf16x8*)&ldsB[(ni * 16 + lrow) * BK + ch];
#pragma unroll
    for (int mi = 0; mi < 2; ++mi) {
      const unsigned int byte =
          (unsigned int)((abits[mi][c >> 3] >> ((c & 7) * 8)) & 0xFFu);
      a[mi] = expand8(byte);
    }
#pragma unroll
    for (int mi = 0; mi < 2; ++mi)
#pragma unroll
      for (int ni = 0; ni < 8; ++ni)
        acc[mi][ni] = __builtin_amdgcn_mfma_f32_16x16x32_bf16(
            a[mi], b[ni], acc[mi][ni], 0, 0, 0);
  }

  // Epilogue (R11-verified). 16x16 C/D: col = lane&15, row = quad*4 + reg.
  // Bit-mask from LDS (broadcast), cndmask-adds, 16-lane shuffle reduce, one
  // plain store per (row, nkid). No atomics, no fences.
#pragma unroll
  for (int mi = 0; mi < 2; ++mi) {
#pragma unroll
    for (int r = 0; r < 4; ++r) {
      const int rloc = wave * 32 + mi * 16 + quad * 4 + r;
      const unsigned long long w0 = mbits[rloc * 2];      // cols 0..63
      const unsigned long long w1 = mbits[rloc * 2 + 1];  // cols 64..127
      float s = 0.f;
#pragma unroll
      for (int ni = 0; ni < 4; ++ni)
        s += ((w0 >> (ni * 16 + lrow)) & 1ull) ? acc[mi][ni][r] : 0.f;
#pragma unroll
      for (int ni = 4; ni < 8; ++ni)
        s += ((w1 >> ((ni - 4) * 16 + lrow)) & 1ull) ? acc[mi][ni][r] : 0.f;
#pragma unroll
      for (int off = 1; off < 16; off <<= 1)
        s += __shfl_xor(s, off, 64);
      if (lrow == 0)
        partial[(size_t)(m0 + rloc) * NPART + nkid] = s;
    }
  }
}

// reduce: out[row] = sum of 256 partials. One block per row, coalesced.
__global__ __launch_bounds__(256) void reduce_kernel(
    const float* __restrict__ partial, float* __restrict__ out) {
  const int row = blockIdx.x;
  const int tid = threadIdx.x;
  float v = partial[(size_t)row * NPART + tid];
#pragma unroll
  for (int off = 1; off < 64; off <<= 1)
    v += __shfl_xor(v, off, 64);
  __shared__ float wsum[4];
  if ((tid & 63) == 0) wsum[tid >> 6] = v;
  __syncthreads();
  if (tid == 0) out[row] = wsum[0] + wsum[1] + wsum[2] + wsum[3];
}

extern "C" void kernel_launch(void* const* d_in, const int* in_sizes, int n_in,
                              void* d_out, int out_size, void* d_ws, size_t ws_size,
                              hipStream_t stream) {
  const float* x = (const float*)d_in[0];
  const float* Q = (const float*)d_in[1];
  float* out = (float*)d_out;

  bf16_t* qb = (bf16_t*)d_ws;                                                // 8 MB @ 0
  unsigned char* xpack = (unsigned char*)((char*)d_ws + ((size_t)8 << 20));  // 256 KB @ 8M
  float* partial = (float*)((char*)d_ws + ((size_t)9 << 20));                // 1 MB @ 9M

  // 262144 pack threads + 524288 Q threads = 786432 = 3072 blocks
  prep_kernel<<<3072, 256, 0, stream>>>(x, Q, qb, xpack);

  dim3 grid(NKB, B_ROWS / BM, KSPLIT);  // (16, 8, 16) = 2048 blocks
  qubo_kernel<<<grid, dim3(256), 0, stream>>>(qb, xpack, partial);

  reduce_kernel<<<B_ROWS, 256, 0, stream>>>(partial, out);
}